// Round 10
// baseline (208.937 us; speedup 1.0000x reference)
//
#include <hip/hip_runtime.h>

// FComb R10: two-kernel cast+compute.
// K1 cast_pack: LINEAR big-granule streaming read of fm (f32, 113 MB),
//   RNE-convert to bf16 and pack channel-pairs (2c,2c+1) into u32 words in
//   MFMA B-frag order; write 56.5 MB to d_ws. Fixes DRAM page locality of the
//   unavoidable L3-miss stream (fragmented-resident-lines theory, R7-R9).
// K2 fused_mlp_mfma: R9 barrier-free structure; input = 8 packed u32/group
//   (L3-resident, ~3.8 TB/s warm rate), zero input-packing ops.
// Numerics bit-identical to R5-R9 (same cvtpk RNE on same values): 7.8e-3.
// MFMA 32x32x16 layouts (verified): A: row=lane&31, k=16*h+8*(lane>>5)+j;
//   B: same k, col=lane&31; D: col=lane&31, row=(r&3)+8*(r>>2)+4*(lane>>5)

typedef float    f32x16 __attribute__((ext_vector_type(16)));
typedef short    bf16x8 __attribute__((ext_vector_type(8)));
typedef unsigned u32x4  __attribute__((ext_vector_type(4)));

constexpr int NPTS  = 96 * 96 * 96;   // 884736
constexpr int NP4   = NPTS / 4;       // 221184
constexpr int BLOCK = 256;            // 4 waves
constexpr int GPW   = 4;              // 32-pt groups per wave
constexpr int NBLK  = NPTS / (32 * GPW * (BLOCK / 64));   // 1728
constexpr int CASTB = 2048;           // cast grid (grid-stride)

__device__ __forceinline__ unsigned cvtpk(float lo, float hi) {
    unsigned d;
    asm("v_cvt_pk_bf16_f32 %0, %1, %2" : "=v"(d) : "v"(lo), "v"(hi));
    return d;
}
__device__ __forceinline__ float unlo(unsigned d) { return __uint_as_float(d << 16); }

__device__ __forceinline__ bf16x8 mk4(unsigned a, unsigned b, unsigned c, unsigned d) {
    u32x4 u; u.x = a; u.y = b; u.z = c; u.w = d;
    return __builtin_bit_cast(bf16x8, u);
}

__device__ __forceinline__ void swap32(unsigned a, unsigned b, unsigned& x, unsigned& y) {
    auto r = __builtin_amdgcn_permlane32_swap(a, b, false, false);
    x = r[0]; y = r[1];
}

__device__ __forceinline__ void load_wsplit(const float* __restrict__ W, int stride,
                                            int row, int koff, bf16x8& Hf, bf16x8& Lf) {
    const float2* p2 = reinterpret_cast<const float2*>(W + row * stride + koff);
    float2 q0 = p2[0], q1 = p2[1], q2 = p2[2], q3 = p2[3];
    unsigned h0 = cvtpk(q0.x, q0.y), h1 = cvtpk(q1.x, q1.y);
    unsigned h2 = cvtpk(q2.x, q2.y), h3 = cvtpk(q3.x, q3.y);
    unsigned l0 = cvtpk(q0.x - unlo(h0), q0.y - __uint_as_float(h0 & 0xffff0000u));
    unsigned l1 = cvtpk(q1.x - unlo(h1), q1.y - __uint_as_float(h1 & 0xffff0000u));
    unsigned l2 = cvtpk(q2.x - unlo(h2), q2.y - __uint_as_float(h2 & 0xffff0000u));
    unsigned l3 = cvtpk(q3.x - unlo(h3), q3.y - __uint_as_float(h3 & 0xffff0000u));
    Hf = mk4(h0, h1, h2, h3);
    Lf = mk4(l0, l1, l2, l3);
}

__device__ __forceinline__ void pack_frags(const f32x16 acc, bf16x8& F0, bf16x8& F1) {
    unsigned p0 = cvtpk(fmaxf(acc[0],  0.f), fmaxf(acc[1],  0.f));
    unsigned p1 = cvtpk(fmaxf(acc[2],  0.f), fmaxf(acc[3],  0.f));
    unsigned p2 = cvtpk(fmaxf(acc[4],  0.f), fmaxf(acc[5],  0.f));
    unsigned p3 = cvtpk(fmaxf(acc[6],  0.f), fmaxf(acc[7],  0.f));
    unsigned p4 = cvtpk(fmaxf(acc[8],  0.f), fmaxf(acc[9],  0.f));
    unsigned p5 = cvtpk(fmaxf(acc[10], 0.f), fmaxf(acc[11], 0.f));
    unsigned p6 = cvtpk(fmaxf(acc[12], 0.f), fmaxf(acc[13], 0.f));
    unsigned p7 = cvtpk(fmaxf(acc[14], 0.f), fmaxf(acc[15], 0.f));
    unsigned a0, a1, b0, b1, c0, c1, d0, d1;
    swap32(p0, p2, a0, a1); swap32(p1, p3, b0, b1);
    swap32(p4, p6, c0, c1); swap32(p5, p7, d0, d1);
    F0 = mk4(a0, b0, a1, b1);
    F1 = mk4(c0, d0, c1, d1);
}

__device__ __forceinline__ unsigned bias_word(float b) {
    float bhi = unlo(cvtpk(b, b));
    return cvtpk(b, b - bhi);
}

#define WLAYER(acc, WH0, WL0, WH1, WL1, F0, F1)                                   \
    acc = __builtin_amdgcn_mfma_f32_32x32x16_bf16(WH0, F0, acc, 0, 0, 0);         \
    acc = __builtin_amdgcn_mfma_f32_32x32x16_bf16(WL0, F0, acc, 0, 0, 0);         \
    acc = __builtin_amdgcn_mfma_f32_32x32x16_bf16(WH1, F1, acc, 0, 0, 0);         \
    acc = __builtin_amdgcn_mfma_f32_32x32x16_bf16(WL1, F1, acc, 0, 0, 0);

// ======================= K1: streaming cast+pack =======================
// fmbp[c2][p] (u32) = bf16(fm[2c2][p]) | bf16(fm[2c2+1][p])<<16
__global__ __launch_bounds__(256)
void cast_pack(const float* __restrict__ fm, unsigned* __restrict__ fmbp)
{
    const int stride = CASTB * 256;
    const float4* __restrict__ f4 = reinterpret_cast<const float4*>(fm);
    uint4* __restrict__ o4        = reinterpret_cast<uint4*>(fmbp);
    const int total = 16 * NP4;
    for (int i = blockIdx.x * 256 + threadIdx.x; i < total; i += stride) {
        const int c2 = i / NP4;            // magic-mul
        const int j  = i - c2 * NP4;
        float4 A = f4[(2 * c2)     * NP4 + j];
        float4 B = f4[(2 * c2 + 1) * NP4 + j];
        uint4 r;
        r.x = cvtpk(A.x, B.x);
        r.y = cvtpk(A.y, B.y);
        r.z = cvtpk(A.z, B.z);
        r.w = cvtpk(A.w, B.w);
        o4[i] = r;
    }
}

// ======================= K2: fused MLP =======================
// 8 pre-packed u32 loads per group: c2 = 4*hl + i (F0), 8 + 4*hl + i (F1).
#define LOADG(arr, pt)                                                            \
    _Pragma("unroll")                                                             \
    for (int i = 0; i < 4; ++i) {                                                 \
        arr[i]     = fmbp[(4 * hl + i) * NPTS + (pt)];                            \
        arr[4 + i] = fmbp[(8 + 4 * hl + i) * NPTS + (pt)];                        \
    }

#define COMPUTE(arr, pt)                                                          \
    {                                                                             \
        bf16x8 F0 = mk4(arr[0], arr[1], arr[2], arr[3]);                          \
        bf16x8 F1 = mk4(arr[4], arr[5], arr[6], arr[7]);                          \
        f32x16 acc = __builtin_amdgcn_mfma_f32_32x32x16_bf16(Ab1, Bone, zacc, 0, 0, 0); \
        WLAYER(acc, W1h0, W1l0, W1h1, W1l1, F0, F1)                               \
        pack_frags(acc, F0, F1);                                                  \
        acc = __builtin_amdgcn_mfma_f32_32x32x16_bf16(Ab2, Bone, zacc, 0, 0, 0);  \
        WLAYER(acc, W2h0, W2l0, W2h1, W2l1, F0, F1)                               \
        pack_frags(acc, F0, F1);                                                  \
        acc = __builtin_amdgcn_mfma_f32_32x32x16_bf16(Ab3, Bone, zacc, 0, 0, 0);  \
        WLAYER(acc, W3h0, W3l0, W3h1, W3l1, F0, F1)                               \
        float s = 0.f;                                                            \
        _Pragma("unroll")                                                         \
        for (int r = 0; r < 16; ++r) s = fmaf(wlr[r], fmaxf(acc[r], 0.f), s);     \
        unsigned px, py;                                                          \
        swap32(__float_as_uint(s), __float_as_uint(s), px, py);                   \
        float tot = __uint_as_float(px) + __uint_as_float(py) + blv;              \
        if (lane < 32) out[pt] = tot;                                             \
    }

__global__ __launch_bounds__(BLOCK, 3)
void fused_mlp_mfma(const unsigned* __restrict__ fmbp, const float* __restrict__ z,
                    const float* __restrict__ w1, const float* __restrict__ b1,
                    const float* __restrict__ w2, const float* __restrict__ b2,
                    const float* __restrict__ w3, const float* __restrict__ b3,
                    const float* __restrict__ wl, const float* __restrict__ bl,
                    float* __restrict__ out)
{
    const int lane = threadIdx.x & 63;
    const int wid  = blockIdx.x * (BLOCK / 64) + (threadIdx.x >> 6);
    const int hl   = lane >> 5;
    const int col  = lane & 31;
    const int koff = 8 * hl;

    const int p0 = (wid * GPW + 0) * 32 + col;
    const int p1 = (wid * GPW + 1) * 32 + col;
    const int p2 = (wid * GPW + 2) * 32 + col;
    const int p3 = (wid * GPW + 3) * 32 + col;

    // ---- pipeline fill: groups 0 and 1 in flight ----
    unsigned va[8], vb[8];
    LOADG(va, p0)
    LOADG(vb, p1)

    // ---- weight frags, hi+lo split (hides under va/vb flight) ----
    bf16x8 W1h0, W1l0, W1h1, W1l1, W2h0, W2l0, W2h1, W2l1, W3h0, W3l0, W3h1, W3l1;
    load_wsplit(w1, 38, col, 0  + koff, W1h0, W1l0);
    load_wsplit(w1, 38, col, 16 + koff, W1h1, W1l1);
    load_wsplit(w2, 32, col, 0  + koff, W2h0, W2l0);
    load_wsplit(w2, 32, col, 16 + koff, W2h1, W2l1);
    load_wsplit(w3, 32, col, 0  + koff, W3h0, W3l0);
    load_wsplit(w3, 32, col, 16 + koff, W3h1, W3l1);

    // ---- rank-1 bias frags; z folded into b1 ----
    float b1e = b1[col];
    b1e = fmaf(w1[col * 38 + 32], z[0], b1e);
    b1e = fmaf(w1[col * 38 + 33], z[1], b1e);
    b1e = fmaf(w1[col * 38 + 34], z[2], b1e);
    b1e = fmaf(w1[col * 38 + 35], z[3], b1e);
    b1e = fmaf(w1[col * 38 + 36], z[4], b1e);
    b1e = fmaf(w1[col * 38 + 37], z[5], b1e);
    const unsigned zero = 0u;
    bf16x8 Ab1  = mk4(hl ? zero : bias_word(b1e),     zero, zero, zero);
    bf16x8 Ab2  = mk4(hl ? zero : bias_word(b2[col]), zero, zero, zero);
    bf16x8 Ab3  = mk4(hl ? zero : bias_word(b3[col]), zero, zero, zero);
    bf16x8 Bone = mk4(hl ? zero : 0x3F803F80u,        zero, zero, zero);

    f32x16 wlr;
    #pragma unroll
    for (int r = 0; r < 16; ++r) wlr[r] = wl[(r & 3) + 8 * (r >> 2) + 4 * hl];
    const float blv = bl[0];

    f32x16 zacc;
    #pragma unroll
    for (int r = 0; r < 16; ++r) zacc[r] = 0.f;

    // ---- steady state: issue g+2 loads, compute g (counted vmcnt only) ----
    unsigned vc[8];
    LOADG(vc, p2)
    COMPUTE(va, p0)

    unsigned vd[8];
    LOADG(vd, p3)
    COMPUTE(vb, p1)

    COMPUTE(vc, p2)
    COMPUTE(vd, p3)
}

extern "C" void kernel_launch(void* const* d_in, const int* in_sizes, int n_in,
                              void* d_out, int out_size, void* d_ws, size_t ws_size,
                              hipStream_t stream)
{
    const float* fm = (const float*)d_in[0];
    const float* z  = (const float*)d_in[1];
    const float* w1 = (const float*)d_in[2];
    const float* b1 = (const float*)d_in[3];
    const float* w2 = (const float*)d_in[4];
    const float* b2 = (const float*)d_in[5];
    const float* w3 = (const float*)d_in[6];
    const float* b3 = (const float*)d_in[7];
    const float* wl = (const float*)d_in[8];
    const float* bl = (const float*)d_in[9];
    float* out = (float*)d_out;
    unsigned* fmbp = (unsigned*)d_ws;    // 16 * NPTS * 4 B = 56.6 MB

    cast_pack<<<CASTB, 256, 0, stream>>>(fm, fmbp);
    fused_mlp_mfma<<<NBLK, BLOCK, 0, stream>>>(
        fmbp, z, w1, b1, w2, b2, w3, b3, wl, bl, out);
}

// Round 11
// 176.356 us; speedup vs baseline: 1.1847x; 1.1847x over previous
//
#include <hip/hip_runtime.h>

// FComb R11: R8 (best, 180.4us) + NON-TEMPORAL fm staging.
// Single-variable A/B vs R8. Theory: harness's 453MB 0xAA ws-poison leaves L3
// full of DIRTY lines; every cold fm read-miss evicts a dirty line -> ~113MB
// writeback shadow. NT loads (CPol bit1 on gfx940+) don't allocate -> no
// eviction -> no writeback. fm is single-touch so NT costs nothing warm.
// Weights remain cached (reused by all waves). Everything else identical to
// R8 (2-phase dbuf pipeline, weight hi/lo split, rank-1 bias MFMA; 7.8e-3).

typedef float    f32x16 __attribute__((ext_vector_type(16)));
typedef short    bf16x8 __attribute__((ext_vector_type(8)));
typedef unsigned u32x4  __attribute__((ext_vector_type(4)));

constexpr int NPTS  = 96 * 96 * 96;       // 884736
constexpr int TILE  = 256;                // points per tile (32 KB)
constexpr int NT    = 4;                  // tiles per block (consecutive)
constexpr int BLOCK = 256;                // 4 waves
constexpr int NBLK  = NPTS / (TILE * NT); // 864
constexpr int AUX_NT = 2;                 // CPol NT bit (gfx940+): no-allocate

typedef __attribute__((address_space(1))) const void glob_void;
typedef __attribute__((address_space(3))) void lds_void;

__device__ __forceinline__ unsigned cvtpk(float lo, float hi) {
    unsigned d;
    asm("v_cvt_pk_bf16_f32 %0, %1, %2" : "=v"(d) : "v"(lo), "v"(hi));
    return d;
}
__device__ __forceinline__ float unlo(unsigned d) { return __uint_as_float(d << 16); }

__device__ __forceinline__ bf16x8 mk4(unsigned a, unsigned b, unsigned c, unsigned d) {
    u32x4 u; u.x = a; u.y = b; u.z = c; u.w = d;
    return __builtin_bit_cast(bf16x8, u);
}

__device__ __forceinline__ void swap32(unsigned a, unsigned b, unsigned& x, unsigned& y) {
    auto r = __builtin_amdgcn_permlane32_swap(a, b, false, false);
    x = r[0]; y = r[1];
}

__device__ __forceinline__ void load_wsplit(const float* __restrict__ W, int stride,
                                            int row, int koff, bf16x8& Hf, bf16x8& Lf) {
    const float2* p2 = reinterpret_cast<const float2*>(W + row * stride + koff);
    float2 q0 = p2[0], q1 = p2[1], q2 = p2[2], q3 = p2[3];
    unsigned h0 = cvtpk(q0.x, q0.y), h1 = cvtpk(q1.x, q1.y);
    unsigned h2 = cvtpk(q2.x, q2.y), h3 = cvtpk(q3.x, q3.y);
    unsigned l0 = cvtpk(q0.x - unlo(h0), q0.y - __uint_as_float(h0 & 0xffff0000u));
    unsigned l1 = cvtpk(q1.x - unlo(h1), q1.y - __uint_as_float(h1 & 0xffff0000u));
    unsigned l2 = cvtpk(q2.x - unlo(h2), q2.y - __uint_as_float(h2 & 0xffff0000u));
    unsigned l3 = cvtpk(q3.x - unlo(h3), q3.y - __uint_as_float(h3 & 0xffff0000u));
    Hf = mk4(h0, h1, h2, h3);
    Lf = mk4(l0, l1, l2, l3);
}

__device__ __forceinline__ void pack_frags(const f32x16 acc, bf16x8& F0, bf16x8& F1) {
    unsigned p0 = cvtpk(fmaxf(acc[0],  0.f), fmaxf(acc[1],  0.f));
    unsigned p1 = cvtpk(fmaxf(acc[2],  0.f), fmaxf(acc[3],  0.f));
    unsigned p2 = cvtpk(fmaxf(acc[4],  0.f), fmaxf(acc[5],  0.f));
    unsigned p3 = cvtpk(fmaxf(acc[6],  0.f), fmaxf(acc[7],  0.f));
    unsigned p4 = cvtpk(fmaxf(acc[8],  0.f), fmaxf(acc[9],  0.f));
    unsigned p5 = cvtpk(fmaxf(acc[10], 0.f), fmaxf(acc[11], 0.f));
    unsigned p6 = cvtpk(fmaxf(acc[12], 0.f), fmaxf(acc[13], 0.f));
    unsigned p7 = cvtpk(fmaxf(acc[14], 0.f), fmaxf(acc[15], 0.f));
    unsigned a0, a1, b0, b1, c0, c1, d0, d1;
    swap32(p0, p2, a0, a1); swap32(p1, p3, b0, b1);
    swap32(p4, p6, c0, c1); swap32(p5, p7, d0, d1);
    F0 = mk4(a0, b0, a1, b1);
    F1 = mk4(c0, d0, c1, d1);
}

__device__ __forceinline__ unsigned bias_word(float b) {
    float bhi = unlo(cvtpk(b, b));
    return cvtpk(b, b - bhi);
}

#define WLAYER(acc, WH0, WL0, WH1, WL1, F0, F1)                                   \
    acc = __builtin_amdgcn_mfma_f32_32x32x16_bf16(WH0, F0, acc, 0, 0, 0);         \
    acc = __builtin_amdgcn_mfma_f32_32x32x16_bf16(WL0, F0, acc, 0, 0, 0);         \
    acc = __builtin_amdgcn_mfma_f32_32x32x16_bf16(WH1, F1, acc, 0, 0, 0);         \
    acc = __builtin_amdgcn_mfma_f32_32x32x16_bf16(WL1, F1, acc, 0, 0, 0);

__global__ __launch_bounds__(BLOCK, 2)
void fused_mlp_mfma(const float* __restrict__ fm, const float* __restrict__ z,
                    const float* __restrict__ w1, const float* __restrict__ b1,
                    const float* __restrict__ w2, const float* __restrict__ b2,
                    const float* __restrict__ w3, const float* __restrict__ b3,
                    const float* __restrict__ wl, const float* __restrict__ bl,
                    float* __restrict__ out)
{
    __shared__ float lds[2][32][TILE];   // 2 x 32 KB

    const int lane = threadIdx.x & 63;
    const int w    = threadIdx.x >> 6;   // wave 0..3
    const int hl   = lane >> 5;
    const int col  = lane & 31;
    const int koff = 8 * hl;
    const int rot  = blockIdx.x & 31;    // per-block channel issue rotation
    const int base = blockIdx.x * (TILE * NT);

    // ---- prologue: stage tile 0 into buf 0 (NT: no L3 allocation) ----
    #pragma unroll
    for (int i = 0; i < 8; ++i) {
        const int c = (w * 8 + i + rot) & 31;
        __builtin_amdgcn_global_load_lds((glob_void*)(fm + c * NPTS + base + lane * 4),
                                         (lds_void*)&lds[0][c][0], 16, 0, AUX_NT);
    }

    // ---- weight frags, hi+lo split (cached; overlaps stage flight) ----
    bf16x8 W1h0, W1l0, W1h1, W1l1, W2h0, W2l0, W2h1, W2l1, W3h0, W3l0, W3h1, W3l1;
    load_wsplit(w1, 38, col, 0  + koff, W1h0, W1l0);
    load_wsplit(w1, 38, col, 16 + koff, W1h1, W1l1);
    load_wsplit(w2, 32, col, 0  + koff, W2h0, W2l0);
    load_wsplit(w2, 32, col, 16 + koff, W2h1, W2l1);
    load_wsplit(w3, 32, col, 0  + koff, W3h0, W3l0);
    load_wsplit(w3, 32, col, 16 + koff, W3h1, W3l1);

    // ---- rank-1 bias frags; z folded into b1 ----
    float b1e = b1[col];
    b1e = fmaf(w1[col * 38 + 32], z[0], b1e);
    b1e = fmaf(w1[col * 38 + 33], z[1], b1e);
    b1e = fmaf(w1[col * 38 + 34], z[2], b1e);
    b1e = fmaf(w1[col * 38 + 35], z[3], b1e);
    b1e = fmaf(w1[col * 38 + 36], z[4], b1e);
    b1e = fmaf(w1[col * 38 + 37], z[5], b1e);
    const unsigned zero = 0u;
    bf16x8 Ab1  = mk4(hl ? zero : bias_word(b1e),     zero, zero, zero);
    bf16x8 Ab2  = mk4(hl ? zero : bias_word(b2[col]), zero, zero, zero);
    bf16x8 Ab3  = mk4(hl ? zero : bias_word(b3[col]), zero, zero, zero);
    bf16x8 Bone = mk4(hl ? zero : 0x3F803F80u,        zero, zero, zero);

    f32x16 wlr;
    #pragma unroll
    for (int r = 0; r < 16; ++r) wlr[r] = wl[(r & 3) + 8 * (r >> 2) + 4 * hl];
    const float blv = bl[0];

    f32x16 zacc;
    #pragma unroll
    for (int r = 0; r < 16; ++r) zacc[r] = 0.f;

    __syncthreads();   // tile 0 staged

    // ---- 2-phase main loop over NT consecutive tiles ----
    #pragma unroll
    for (int t = 0; t < NT; ++t) {
        const int cur = t & 1;

        // issue next tile's stage BEFORE computing current (flight hides here)
        if (t + 1 < NT) {
            const int tb2 = base + (t + 1) * TILE;
            #pragma unroll
            for (int i = 0; i < 8; ++i) {
                const int c = (w * 8 + i + rot) & 31;
                __builtin_amdgcn_global_load_lds((glob_void*)(fm + c * NPTS + tb2 + lane * 4),
                                                 (lds_void*)&lds[cur ^ 1][c][0], 16, 0, AUX_NT);
            }
        }

        // compute: this wave's 2 point-groups of 32
        #pragma unroll
        for (int g = 0; g < 2; ++g) {
            const int pl = (w * 2 + g) * 32 + col;

            float v0  = lds[cur][koff + 0][pl],  v1  = lds[cur][koff + 1][pl];
            float v2  = lds[cur][koff + 2][pl],  v3  = lds[cur][koff + 3][pl];
            float v4  = lds[cur][koff + 4][pl],  v5  = lds[cur][koff + 5][pl];
            float v6  = lds[cur][koff + 6][pl],  v7  = lds[cur][koff + 7][pl];
            float v8  = lds[cur][16 + koff + 0][pl], v9  = lds[cur][16 + koff + 1][pl];
            float v10 = lds[cur][16 + koff + 2][pl], v11 = lds[cur][16 + koff + 3][pl];
            float v12 = lds[cur][16 + koff + 4][pl], v13 = lds[cur][16 + koff + 5][pl];
            float v14 = lds[cur][16 + koff + 6][pl], v15 = lds[cur][16 + koff + 7][pl];

            bf16x8 F0 = mk4(cvtpk(v0, v1),  cvtpk(v2, v3),
                            cvtpk(v4, v5),  cvtpk(v6, v7));
            bf16x8 F1 = mk4(cvtpk(v8, v9),  cvtpk(v10, v11),
                            cvtpk(v12, v13), cvtpk(v14, v15));

            f32x16 acc = __builtin_amdgcn_mfma_f32_32x32x16_bf16(Ab1, Bone, zacc, 0, 0, 0);
            WLAYER(acc, W1h0, W1l0, W1h1, W1l1, F0, F1)

            pack_frags(acc, F0, F1);
            acc = __builtin_amdgcn_mfma_f32_32x32x16_bf16(Ab2, Bone, zacc, 0, 0, 0);
            WLAYER(acc, W2h0, W2l0, W2h1, W2l1, F0, F1)

            pack_frags(acc, F0, F1);
            acc = __builtin_amdgcn_mfma_f32_32x32x16_bf16(Ab3, Bone, zacc, 0, 0, 0);
            WLAYER(acc, W3h0, W3l0, W3h1, W3l1, F0, F1)

            float s = 0.f;
            #pragma unroll
            for (int r = 0; r < 16; ++r) s = fmaf(wlr[r], fmaxf(acc[r], 0.f), s);
            unsigned px, py;
            swap32(__float_as_uint(s), __float_as_uint(s), px, py);
            float tot = __uint_as_float(px) + __uint_as_float(py) + blv;
            if (lane < 32)
                __builtin_nontemporal_store(tot, &out[base + t * TILE + pl]);
        }

        __syncthreads();   // drains next-tile stage + buffer handoff
    }
}

extern "C" void kernel_launch(void* const* d_in, const int* in_sizes, int n_in,
                              void* d_out, int out_size, void* d_ws, size_t ws_size,
                              hipStream_t stream)
{
    const float* fm = (const float*)d_in[0];
    const float* z  = (const float*)d_in[1];
    const float* w1 = (const float*)d_in[2];
    const float* b1 = (const float*)d_in[3];
    const float* w2 = (const float*)d_in[4];
    const float* b2 = (const float*)d_in[5];
    const float* w3 = (const float*)d_in[6];
    const float* b3 = (const float*)d_in[7];
    const float* wl = (const float*)d_in[8];
    const float* bl = (const float*)d_in[9];
    float* out = (float*)d_out;

    fused_mlp_mfma<<<NBLK, BLOCK, 0, stream>>>(
        fm, z, w1, b1, w2, b2, w3, b3, wl, bl, out);
}